// Round 5
// baseline (372.642 us; speedup 1.0000x reference)
//
#include <hip/hip_runtime.h>
#include <hip/hip_bf16.h>

// GCN: 2x GCNConv(128->128) + LeakyReLU(0.1) + mean over channels.
// N=50000, E=1600000, D=128, fp32 in/out.
//
// R5: (a) channel-quartered gather: g16 stored as 4 quarter-major tables of
//     3.2MB (<= 4MB per-XCD L2); 4 serialized passes => gathers become L2
//     hits (R4: 208MB TCC FETCH, 64us, L3-latency bound).
//     (b) GEMM TM=32, LDS 48KB -> 3 blocks/CU (12 waves/CU).
//     (c) combine+scan_partial fused; deg array dropped.
//     count_rank kept (64us): device-scope atomics resolve memory-side --
//     XCD partitioning can't reduce their RMW traffic (R4 evidence).
// Math (verified R2-R4): g[u]=dinv[u]*(x@W1)[u]  (bf16-packed);
//   mg[u]=dinv[u]*dot(lrelu(dinv[u]*(g[u]+sum g[nbr]) + b1), mean_j W2[:,j]);
//   out[v]=dinv[v]*(mg[v]+sum mg[nbr]) + mean(b2).

#define N_NODES 50000
#define NPAD 50048
#define D 128

typedef unsigned int uint;
typedef unsigned short u16;

__device__ __forceinline__ uint pack_bf2(float a, float b) {
    uint ua = __float_as_uint(a), ub = __float_as_uint(b);
    ua = (ua + 0x7fffu + ((ua >> 16) & 1u)) >> 16;   // RNE
    ub = (ub + 0x7fffu + ((ub >> 16) & 1u)) >> 16;
    return ua | (ub << 16);
}

// ---------------- partitioned degree histogram + per-edge local rank ----------------
__global__ void count_rank_kernel(const int* __restrict__ dst, uint* __restrict__ cnt,
                                  u16* __restrict__ rank, int E) {
    int e = blockIdx.x * blockDim.x + threadIdx.x;
    if (e >= E) return;
    int part = blockIdx.x & 7;                 // same partition recomputed in fill
    rank[e] = (u16)atomicAdd(&cnt[part * NPAD + dst[e]], 1u);
}

// fused: per-partition prefix (xoff) + dinv + block-local exclusive scan of deg
__global__ void combine_scan_kernel(const uint* __restrict__ cnt, float* __restrict__ dinv,
                                    u16* __restrict__ xoff, int* __restrict__ row,
                                    unsigned* __restrict__ bsum, int N) {
    __shared__ unsigned s[256];
    int t = threadIdx.x;
    int i = blockIdx.x * 256 + t;
    unsigned run = 0;
    if (i < N) {
#pragma unroll
        for (int x = 0; x < 8; x++) {
            xoff[x * NPAD + i] = (u16)run;
            run += cnt[x * NPAD + i];
        }
        dinv[i] = rsqrtf((float)(run + 1u));   // +1 self-loop
    }
    s[t] = run;
    __syncthreads();
#pragma unroll
    for (int off = 1; off < 256; off <<= 1) {
        unsigned u = (t >= off) ? s[t - off] : 0u;
        __syncthreads();
        s[t] += u;
        __syncthreads();
    }
    if (i < N) row[i] = (int)(s[t] - run);
    if (t == 255) bsum[blockIdx.x] = s[255];
}

__global__ void scan_top_kernel(unsigned* __restrict__ bsum, int* __restrict__ row,
                                int nblocks, int N, int E) {
    __shared__ unsigned s[256];
    int t = threadIdx.x;
    unsigned v = (t < nblocks) ? bsum[t] : 0u;
    s[t] = v;
    __syncthreads();
#pragma unroll
    for (int off = 1; off < 256; off <<= 1) {
        unsigned u = (t >= off) ? s[t - off] : 0u;
        __syncthreads();
        s[t] += u;
        __syncthreads();
    }
    if (t < nblocks) bsum[t] = s[t] - v;
    if (t == 0) row[N] = E;
}

__global__ void scan_add_kernel(int* __restrict__ row, const unsigned* __restrict__ bsum, int N) {
    int i = blockIdx.x * 256 + threadIdx.x;
    if (i < N) row[i] += (int)bsum[blockIdx.x];
}

// ---------------- CSR fill (atomic-free) ----------------
__global__ void fill_kernel(const int* __restrict__ src, const int* __restrict__ dst,
                            const int* __restrict__ row, const u16* __restrict__ rank,
                            const u16* __restrict__ xoff, u16* __restrict__ esrc, int E) {
    int e = blockIdx.x * blockDim.x + threadIdx.x;
    if (e >= E) return;
    int part = blockIdx.x & 7;
    int d = dst[e];
    esrc[row[d] + (int)xoff[part * NPAD + d] + (int)rank[e]] = (u16)src[e];
}

// ---------------- w2m = mean_j W2[k,j]; w2m[128] = mean(b2) ----------------
__global__ void w2m_kernel(const float* __restrict__ W2, const float* __restrict__ b2,
                           float* __restrict__ w2m) {
    int k = threadIdx.x;   // 128 threads
    float s = 0.f;
    for (int j = 0; j < 128; j++) s += W2[k * 128 + j];
    w2m[k] = s * (1.0f / 128.0f);
    if (k == 0) {
        float t = 0.f;
        for (int j = 0; j < 128; j++) t += b2[j];
        w2m[128] = t * (1.0f / 128.0f);
    }
}

// ---------------- GEMM: quarter-major g16 = pack_bf16( dinv[row] * (A @ W) ) ----------------
// TM=32: As 16KB + Ws K-slice 32KB = 48KB -> 3 blocks/CU.
#define TM 32
__global__ __launch_bounds__(256) void gemm_kernel(
    const float* __restrict__ A, const float* __restrict__ W,
    uint* __restrict__ G16, const float* __restrict__ dinv, int M) {
    __shared__ float Ws[64 * 128];    // 32 KB (K-slice)
    __shared__ float As[TM * 128];    // 16 KB
    int t = threadIdx.x;
    int row0 = blockIdx.x * TM;

    {   // stage A tile (full K): 1024 float4, 4 per thread
        float4* Asv = (float4*)As;
#pragma unroll
        for (int i = 0; i < 4; i++) {
            int f = t + i * 256;
            int r = f >> 5;
            int c4 = f & 31;
            int row = row0 + r;
            float4 v = make_float4(0.f, 0.f, 0.f, 0.f);
            if (row < M) v = ((const float4*)(A + (long)row * D))[c4];
            Asv[f] = v;
        }
    }

    int tx = t & 31;   // cols 4tx..4tx+3
    int ty = t >> 5;   // rows ty*4..ty*4+3
    float4 acc[4];
#pragma unroll
    for (int r = 0; r < 4; r++) acc[r] = make_float4(0.f, 0.f, 0.f, 0.f);

    const float4* Wsv = (const float4*)Ws;
    for (int ph = 0; ph < 2; ph++) {
        __syncthreads();
        {   // stage W K-slice rows ph*64..ph*64+63
            const float4* Wv = (const float4*)(W + ph * 64 * 128);
            float4* Wsv_w = (float4*)Ws;
#pragma unroll
            for (int i = 0; i < 8; i++) Wsv_w[t + i * 256] = Wv[t + i * 256];
        }
        __syncthreads();
        for (int k = 0; k < 64; k += 4) {
            float4 w0 = Wsv[(k + 0) * 32 + tx];
            float4 w1 = Wsv[(k + 1) * 32 + tx];
            float4 w2 = Wsv[(k + 2) * 32 + tx];
            float4 w3 = Wsv[(k + 3) * 32 + tx];
#pragma unroll
            for (int r = 0; r < 4; r++) {
                int row = ty * 4 + r;
                float4 a = *(const float4*)(As + row * 128 + ph * 64 + k);
                acc[r].x += a.x * w0.x + a.y * w1.x + a.z * w2.x + a.w * w3.x;
                acc[r].y += a.x * w0.y + a.y * w1.y + a.z * w2.y + a.w * w3.y;
                acc[r].z += a.x * w0.z + a.y * w1.z + a.z * w2.z + a.w * w3.z;
                acc[r].w += a.x * w0.w + a.y * w1.w + a.z * w2.w + a.w * w3.w;
            }
        }
    }
    // epilogue: quarter-major layout. quarter q = tx>>3, uint2 slot = tx&7.
#pragma unroll
    for (int r = 0; r < 4; r++) {
        int row = row0 + ty * 4 + r;
        if (row < M) {
            float dv = dinv[row];
            uint2 o;
            o.x = pack_bf2(acc[r].x * dv, acc[r].y * dv);
            o.y = pack_bf2(acc[r].z * dv, acc[r].w * dv);
            ((uint2*)G16)[((long)(tx >> 3) * NPAD + row) * 8 + (tx & 7)] = o;
        }
    }
}

// ---------------- gather pass q: 32 channels, L2-resident 3.2MB table ----------------
// One wave per node; 8 lanes (uint2) per quarter-row; 8 neighbors in flight.
__global__ __launch_bounds__(256) void gather_pass_kernel(
    const int* __restrict__ row, const u16* __restrict__ esrc,
    const uint* __restrict__ g16, const float* __restrict__ dinv,
    const float* __restrict__ b1, const float* __restrict__ w2m,
    float* __restrict__ partial, int q, int N) {
    int wave = threadIdx.x >> 6;
    int lane = threadIdx.x & 63;
    int sub = lane & 7;        // uint2 slot within 64B quarter-row
    int nb = lane >> 3;        // neighbor slot (8 concurrent)
    int v = blockIdx.x * 4 + wave;
    if (v >= N) return;

    const uint2* gq = (const uint2*)g16 + (long)q * NPAD * 8;
    float a0 = 0.f, a1 = 0.f, a2 = 0.f, a3 = 0.f;

#define ACC2(u)                                                          \
    a0 += __uint_as_float((u).x << 16); a1 += __uint_as_float((u).x & 0xffff0000u); \
    a2 += __uint_as_float((u).y << 16); a3 += __uint_as_float((u).y & 0xffff0000u);

    if (nb == 0) {             // self-loop term
        uint2 u = gq[(long)v * 8 + sub];
        ACC2(u)
    }
    int jb = row[v], je = row[v + 1];
    int j = jb + nb;
    if (j < je) {              // 2-deep software pipeline per neighbor chain
        uint2 u = gq[(long)esrc[j] * 8 + sub];
        j += 8;
        while (j < je) {
            uint2 u2 = gq[(long)esrc[j] * 8 + sub];
            j += 8;
            ACC2(u)
            u = u2;
        }
        ACC2(u)
    }
#undef ACC2

    // reduce over the 8 neighbor groups
#define RED(a) a += __shfl_xor(a, 8, 64); a += __shfl_xor(a, 16, 64); a += __shfl_xor(a, 32, 64);
    RED(a0) RED(a1) RED(a2) RED(a3)
#undef RED

    if (nb == 0) {             // lanes 0..7: channels q*32 + sub*4 .. +3
        float dv = dinv[v];
        float4 bb = ((const float4*)b1)[q * 8 + sub];
        float4 wm = ((const float4*)w2m)[q * 8 + sub];
        float t0 = dv * a0 + bb.x; t0 = t0 >= 0.f ? t0 : 0.1f * t0;
        float t1 = dv * a1 + bb.y; t1 = t1 >= 0.f ? t1 : 0.1f * t1;
        float t2 = dv * a2 + bb.z; t2 = t2 >= 0.f ? t2 : 0.1f * t2;
        float t3 = dv * a3 + bb.w; t3 = t3 >= 0.f ? t3 : 0.1f * t3;
        float s = t0 * wm.x + t1 * wm.y + t2 * wm.z + t3 * wm.w;
        s += __shfl_xor(s, 1, 64);
        s += __shfl_xor(s, 2, 64);
        s += __shfl_xor(s, 4, 64);
        if (sub == 0) partial[q * NPAD + v] = s;
    }
}

// ---------------- mg[v] = dinv[v] * sum_q partial[q][v] ----------------
__global__ void mg_kernel(const float* __restrict__ partial, const float* __restrict__ dinv,
                          float* __restrict__ mg, int N) {
    int v = blockIdx.x * blockDim.x + threadIdx.x;
    if (v >= N) return;
    mg[v] = dinv[v] * (partial[v] + partial[NPAD + v] + partial[2 * NPAD + v] + partial[3 * NPAD + v]);
}

// ---------------- scalar aggregate for conv2 + mean ----------------
__global__ void out_kernel(const int* __restrict__ row, const u16* __restrict__ esrc,
                           const float* __restrict__ mg, const float* __restrict__ dinv,
                           const float* __restrict__ w2m, float* __restrict__ out, int N) {
    int v = blockIdx.x * blockDim.x + threadIdx.x;
    if (v >= N) return;
    float acc = mg[v];
    int jb = row[v], je = row[v + 1];
    int j = jb;
    for (; j + 8 <= je; j += 8) {
        acc += mg[esrc[j]] + mg[esrc[j + 1]] + mg[esrc[j + 2]] + mg[esrc[j + 3]] +
               mg[esrc[j + 4]] + mg[esrc[j + 5]] + mg[esrc[j + 6]] + mg[esrc[j + 7]];
    }
    for (; j < je; j++) acc += mg[esrc[j]];
    out[v] = dinv[v] * acc + w2m[128];
}

extern "C" void kernel_launch(void* const* d_in, const int* in_sizes, int n_in,
                              void* d_out, int out_size, void* d_ws, size_t ws_size,
                              hipStream_t stream) {
    const float* x  = (const float*)d_in[0];
    const int* ei   = (const int*)d_in[1];
    const float* W1 = (const float*)d_in[2];
    const float* b1 = (const float*)d_in[3];
    const float* W2 = (const float*)d_in[4];
    const float* b2 = (const float*)d_in[5];
    float* out = (float*)d_out;

    const int N = N_NODES;
    const int E = in_sizes[1] / 2;
    const int* src = ei;
    const int* dst = ei + E;
    const int nblocks = (N + 255) / 256;     // 196

    // workspace layout (4B units). rank & cnt alias g16 (dead before gemm writes it).
    float*    dinv  = (float*)d_ws;                       // [NPAD]
    int*      row   = (int*)(dinv + NPAD);                // [N+1 -> NPAD+16]
    unsigned* bsum  = (unsigned*)(row + NPAD + 16);       // [256]
    float*    w2m   = (float*)(bsum + 256);               // [256] ([128]=mean b2)
    float*    mg    = w2m + 256;                          // [NPAD]
    float*    partial = mg + NPAD;                        // [4*NPAD]
    u16*      xoff  = (u16*)(partial + 4 * NPAD);         // [8*NPAD] u16
    u16*      esrc  = xoff + 8 * NPAD;                    // [E] u16
    uint*     g16   = (uint*)(esrc + E + (E & 1));        // [NPAD*64] quarter-major
    u16*      rank  = (u16*)g16;                          // [E] u16   (alias, dead after fill)
    uint*     cnt   = g16 + E / 2;                        // [8*NPAD]  (alias, dead after combine)

    hipMemsetAsync(cnt, 0, 8 * NPAD * sizeof(uint), stream);

    // partitioned histogram + local rank
    count_rank_kernel<<<(E + 255) / 256, 256, 0, stream>>>(dst, cnt, rank, E);

    // xoff/dinv + scan -> row
    combine_scan_kernel<<<nblocks, 256, 0, stream>>>(cnt, dinv, xoff, row, bsum, N);
    scan_top_kernel<<<1, 256, 0, stream>>>(bsum, row, nblocks, N, E);
    scan_add_kernel<<<nblocks, 256, 0, stream>>>(row, bsum, N);
    fill_kernel<<<(E + 255) / 256, 256, 0, stream>>>(src, dst, row, rank, xoff, esrc, E);

    // w2m / mean(b2)
    w2m_kernel<<<1, 128, 0, stream>>>(W2, b2, w2m);

    // g16 = bf16( dinv * (x @ W1) ), quarter-major   (clobbers rank/cnt aliases)
    gemm_kernel<<<(N + TM - 1) / TM, 256, 0, stream>>>(x, W1, g16, dinv, N);

    // 4 L2-resident gather passes (32 channels each)
    for (int q = 0; q < 4; q++)
        gather_pass_kernel<<<(N + 3) / 4, 256, 0, stream>>>(row, esrc, g16, dinv, b1, w2m,
                                                            partial, q, N);
    mg_kernel<<<nblocks, 256, 0, stream>>>(partial, dinv, mg, N);

    // out[v] = dinv[v] * (mg[v] + sum mg[nbr]) + mean(b2)
    out_kernel<<<nblocks, 256, 0, stream>>>(row, esrc, mg, dinv, w2m, out, N);
}

// Round 6
// 239.414 us; speedup vs baseline: 1.5565x; 1.5565x over previous
//
#include <hip/hip_runtime.h>
#include <hip/hip_bf16.h>

// GCN: 2x GCNConv(128->128) + LeakyReLU(0.1) + mean over channels.
// N=50000, E=1600000, D=128, fp32 in/out.
//
// R6: atomic-free CSR build via two-level bucket sort (bucket = dst>>8, 196
//     buckets; LDS atomics only). Replaces count_rank (64us: 1.6M returning
//     device atomics = memory-side floor, R3/R4 evidence) + fill (25us: 2B
//     scatter, 16x write amplification). gemm/gather reverted to R4 versions
//     (R5's TM=32 blew VGPR to 216; quartered gather thrashed L2 because
//     per-pass working set 6.6MB > 4MB/XCD L2).
// Math (verified R2-R5): g[u]=dinv[u]*(x@W1)[u]  (bf16-packed);
//   mg[u]=dinv[u]*dot(lrelu(dinv[u]*(g[u]+sum g[nbr]) + b1), mean_j W2[:,j]);
//   out[v]=dinv[v]*(mg[v]+sum mg[nbr]) + mean(b2).

#define N_NODES 50000
#define NPAD 50048
#define D 128
#define BK 196           // node buckets: v>>8  (50000/256 -> 196)
#define CHUNK 4096       // edges per stage-1 block

typedef unsigned int uint;
typedef unsigned short u16;

__device__ __forceinline__ uint pack_bf2(float a, float b) {
    uint ua = __float_as_uint(a), ub = __float_as_uint(b);
    ua = (ua + 0x7fffu + ((ua >> 16) & 1u)) >> 16;   // RNE
    ub = (ub + 0x7fffu + ((ub >> 16) & 1u)) >> 16;
    return ua | (ub << 16);
}

// ---------------- stage 1: per-chunk bucket histogram (LDS atomics) ----------------
__global__ void hist_kernel(const int* __restrict__ dst, uint* __restrict__ H, int E, int CHN) {
    __shared__ uint h[BK];
    int t = threadIdx.x, c = blockIdx.x;
    if (t < BK) h[t] = 0;
    __syncthreads();
    int e0 = c * CHUNK;
    for (int i = t; i < CHUNK; i += 256) {
        int e = e0 + i;
        if (e < E) atomicAdd(&h[dst[e] >> 8], 1u);
    }
    __syncthreads();
    if (t < BK) H[t * CHN + c] = h[t];     // bucket-major for column scan
}

// per-bucket exclusive scan over chunks (in place); totals -> T
__global__ void colscan_kernel(uint* __restrict__ H, uint* __restrict__ T, int CHN) {
    __shared__ uint s[256];
    int t = threadIdx.x, b = blockIdx.x;
    uint carry = 0;
    for (int base = 0; base < CHN; base += 256) {
        int idx = base + t;
        uint v = (idx < CHN) ? H[b * CHN + idx] : 0u;
        s[t] = v;
        __syncthreads();
#pragma unroll
        for (int off = 1; off < 256; off <<= 1) {
            uint u = (t >= off) ? s[t - off] : 0u;
            __syncthreads();
            s[t] += u;
            __syncthreads();
        }
        if (idx < CHN) H[b * CHN + idx] = carry + s[t] - v;   // exclusive + carry
        carry += s[255];
        __syncthreads();
    }
    if (t == 0) T[b] = carry;
}

// exclusive scan of bucket totals -> B[0..BK]; row[N]=E
__global__ void totscan_kernel(const uint* __restrict__ T, uint* __restrict__ B,
                               int* __restrict__ row, int E, int N) {
    __shared__ uint s[256];
    int t = threadIdx.x;
    uint v = (t < BK) ? T[t] : 0u;
    s[t] = v;
    __syncthreads();
#pragma unroll
    for (int off = 1; off < 256; off <<= 1) {
        uint u = (t >= off) ? s[t - off] : 0u;
        __syncthreads();
        s[t] += u;
        __syncthreads();
    }
    if (t < BK) B[t] = s[t] - v;
    if (t == 0) { B[BK] = (uint)E; row[N] = E; }
}

// scatter edges into bucket regions (LDS cursors; order within bucket arbitrary)
__global__ void scatter_kernel(const int* __restrict__ src, const int* __restrict__ dst,
                               const uint* __restrict__ H, const uint* __restrict__ B,
                               uint* __restrict__ EB, int E, int CHN) {
    __shared__ uint cur[BK];
    int t = threadIdx.x, c = blockIdx.x;
    if (t < BK) cur[t] = B[t] + H[t * CHN + c];
    __syncthreads();
    int e0 = c * CHUNK;
    for (int i = t; i < CHUNK; i += 256) {
        int e = e0 + i;
        if (e < E) {
            int d = dst[e];
            uint slot = atomicAdd(&cur[d >> 8], 1u);
            EB[slot] = ((uint)(d & 255) << 16) | (uint)src[e];
        }
    }
}

// stage 2: per-bucket counting sort by dst&255 -> esrc, row, dinv (dense writes)
__global__ void bucket_sort_kernel(const uint* __restrict__ EB, const uint* __restrict__ B,
                                   int* __restrict__ row, float* __restrict__ dinv,
                                   u16* __restrict__ esrc, int N) {
    __shared__ uint cnt[256], s[256], cur[256];
    int t = threadIdx.x, b = blockIdx.x;
    uint base = B[b], ne = B[b + 1] - base;
    cnt[t] = 0;
    __syncthreads();
    for (uint i = t; i < ne; i += 256) atomicAdd(&cnt[EB[base + i] >> 16], 1u);
    __syncthreads();
    uint c = cnt[t];
    s[t] = c;
    __syncthreads();
#pragma unroll
    for (int off = 1; off < 256; off <<= 1) {
        uint u = (t >= off) ? s[t - off] : 0u;
        __syncthreads();
        s[t] += u;
        __syncthreads();
    }
    uint p = s[t] - c;                      // exclusive prefix within bucket
    int v = (b << 8) + t;
    if (v < N) {
        row[v] = (int)(base + p);
        dinv[v] = rsqrtf((float)(c + 1u));  // +1 self-loop
    }
    cur[t] = base + p;
    __syncthreads();
    for (uint i = t; i < ne; i += 256) {
        uint u = EB[base + i];
        uint slot = atomicAdd(&cur[u >> 16], 1u);
        esrc[slot] = (u16)(u & 0xffffu);
    }
}

// ---------------- w2m[k] = mean_j W2[k,j]; w2m[128] = mean(b2) ----------------
__global__ void w2m_kernel(const float* __restrict__ W2, const float* __restrict__ b2,
                           float* __restrict__ w2m) {
    int k = blockIdx.x, lane = threadIdx.x;   // grid 129 x 64
    const float* p = (k < 128) ? (W2 + k * 128) : b2;
    float s = p[lane] + p[lane + 64];
#pragma unroll
    for (int off = 32; off > 0; off >>= 1) s += __shfl_down(s, off, 64);
    if (lane == 0) w2m[k] = s * (1.0f / 128.0f);
}

// ---------------- GEMM: g16[M,64] = pack_bf16( dinv[row] * (A @ W) ) ----------------
// R4 version: TM=64, two-phase 32KB W K-slices, LDS 64KB.
#define TM 64
__global__ __launch_bounds__(256) void gemm_kernel(
    const float* __restrict__ A, const float* __restrict__ W,
    uint* __restrict__ G16, const float* __restrict__ dinv, int M) {
    __shared__ float Ws[64 * 128];    // 32 KB (K-slice)
    __shared__ float As[TM * 128];    // 32 KB
    int t = threadIdx.x;
    int row0 = blockIdx.x * TM;

    {   // stage A tile (full K)
        float4* Asv = (float4*)As;
#pragma unroll
        for (int i = 0; i < (TM * 32) / 256; i++) {
            int f = t + i * 256;
            int r = f >> 5;
            int c4 = f & 31;
            int row = row0 + r;
            float4 v = make_float4(0.f, 0.f, 0.f, 0.f);
            if (row < M) v = ((const float4*)(A + (long)row * D))[c4];
            Asv[f] = v;
        }
    }

    int tx = t & 31;
    int ty = t >> 5;
    float4 acc[8];
#pragma unroll
    for (int r = 0; r < 8; r++) acc[r] = make_float4(0.f, 0.f, 0.f, 0.f);

    const float4* Wsv = (const float4*)Ws;
    for (int ph = 0; ph < 2; ph++) {
        __syncthreads();
        {   // stage W K-slice rows ph*64..ph*64+63
            const float4* Wv = (const float4*)(W + ph * 64 * 128);
            float4* Wsv_w = (float4*)Ws;
#pragma unroll
            for (int i = 0; i < 8; i++) Wsv_w[t + i * 256] = Wv[t + i * 256];
        }
        __syncthreads();
        for (int k = 0; k < 64; k += 4) {
            float4 w0 = Wsv[(k + 0) * 32 + tx];
            float4 w1 = Wsv[(k + 1) * 32 + tx];
            float4 w2 = Wsv[(k + 2) * 32 + tx];
            float4 w3 = Wsv[(k + 3) * 32 + tx];
#pragma unroll
            for (int r = 0; r < 8; r++) {
                int row = ty * 8 + r;
                float4 a = *(const float4*)(As + row * 128 + ph * 64 + k);
                acc[r].x += a.x * w0.x + a.y * w1.x + a.z * w2.x + a.w * w3.x;
                acc[r].y += a.x * w0.y + a.y * w1.y + a.z * w2.y + a.w * w3.y;
                acc[r].z += a.x * w0.z + a.y * w1.z + a.z * w2.z + a.w * w3.z;
                acc[r].w += a.x * w0.w + a.y * w1.w + a.z * w2.w + a.w * w3.w;
            }
        }
    }
#pragma unroll
    for (int r = 0; r < 8; r++) {
        int row = row0 + ty * 8 + r;
        if (row < M) {
            float dv = dinv[row];
            uint2 o;
            o.x = pack_bf2(acc[r].x * dv, acc[r].y * dv);
            o.y = pack_bf2(acc[r].z * dv, acc[r].w * dv);
            ((uint2*)G16)[(long)row * 32 + tx] = o;
        }
    }
}

// ---------------- fused gather(bf16) + leakyrelu + dot(w2m) ----------------
// R4 version: one wave/node; 16 lanes (uint4) cover 256B row; 4 neighbor chains, unroll 2.
__global__ __launch_bounds__(256) void gather_node_kernel(
    const int* __restrict__ row, const u16* __restrict__ esrc,
    const uint* __restrict__ g16, const float* __restrict__ dinv,
    const float* __restrict__ b1, const float* __restrict__ w2m,
    float* __restrict__ mg, int N) {
    int wave = threadIdx.x >> 6;
    int lane = threadIdx.x & 63;
    int sub = lane & 15;       // uint4 slot within row
    int grp = lane >> 4;       // neighbor slot (4 concurrent)
    int v = blockIdx.x * 4 + wave;
    if (v >= N) return;

    const uint4* gv = (const uint4*)g16;   // row stride = 16 uint4
    float a0 = 0.f, a1 = 0.f, a2 = 0.f, a3 = 0.f, a4 = 0.f, a5 = 0.f, a6 = 0.f, a7 = 0.f;

#define ACCUM(u)                                                        \
    a0 += __uint_as_float((u).x << 16); a1 += __uint_as_float((u).x & 0xffff0000u); \
    a2 += __uint_as_float((u).y << 16); a3 += __uint_as_float((u).y & 0xffff0000u); \
    a4 += __uint_as_float((u).z << 16); a5 += __uint_as_float((u).z & 0xffff0000u); \
    a6 += __uint_as_float((u).w << 16); a7 += __uint_as_float((u).w & 0xffff0000u);

    if (grp == 0) {            // self-loop term
        uint4 u = gv[(long)v * 16 + sub];
        ACCUM(u)
    }
    int jb = row[v], je = row[v + 1];
    int j = jb + grp;
    for (; j + 4 < je; j += 8) {
        int s0 = esrc[j], s1 = esrc[j + 4];
        uint4 u0 = gv[(long)s0 * 16 + sub];
        uint4 u1 = gv[(long)s1 * 16 + sub];
        ACCUM(u0)
        ACCUM(u1)
    }
    for (; j < je; j += 4) {
        int s = esrc[j];
        uint4 u = gv[(long)s * 16 + sub];
        ACCUM(u)
    }
#undef ACCUM

    // reduce the 4 neighbor groups
#define RED(a) a += __shfl_xor(a, 16, 64); a += __shfl_xor(a, 32, 64);
    RED(a0) RED(a1) RED(a2) RED(a3) RED(a4) RED(a5) RED(a6) RED(a7)
#undef RED

    if (grp == 0) {            // lanes 0..15 hold channels 8*sub .. 8*sub+7
        float dv = dinv[v];
        const float2* bp = (const float2*)b1;
        const float2* wp = (const float2*)w2m;
        float s = 0.f;
        float2 bb, wm;
        bb = bp[4 * sub + 0]; wm = wp[4 * sub + 0];
        float t0 = dv * a0 + bb.x; t0 = t0 >= 0.f ? t0 : 0.1f * t0;
        float t1 = dv * a1 + bb.y; t1 = t1 >= 0.f ? t1 : 0.1f * t1;
        s += t0 * wm.x + t1 * wm.y;
        bb = bp[4 * sub + 1]; wm = wp[4 * sub + 1];
        t0 = dv * a2 + bb.x; t0 = t0 >= 0.f ? t0 : 0.1f * t0;
        t1 = dv * a3 + bb.y; t1 = t1 >= 0.f ? t1 : 0.1f * t1;
        s += t0 * wm.x + t1 * wm.y;
        bb = bp[4 * sub + 2]; wm = wp[4 * sub + 2];
        t0 = dv * a4 + bb.x; t0 = t0 >= 0.f ? t0 : 0.1f * t0;
        t1 = dv * a5 + bb.y; t1 = t1 >= 0.f ? t1 : 0.1f * t1;
        s += t0 * wm.x + t1 * wm.y;
        bb = bp[4 * sub + 3]; wm = wp[4 * sub + 3];
        t0 = dv * a6 + bb.x; t0 = t0 >= 0.f ? t0 : 0.1f * t0;
        t1 = dv * a7 + bb.y; t1 = t1 >= 0.f ? t1 : 0.1f * t1;
        s += t0 * wm.x + t1 * wm.y;
        s += __shfl_xor(s, 1, 64);
        s += __shfl_xor(s, 2, 64);
        s += __shfl_xor(s, 4, 64);
        s += __shfl_xor(s, 8, 64);
        if (sub == 0) mg[v] = dv * s;
    }
}

// ---------------- scalar aggregate for conv2 + mean ----------------
__global__ void out_kernel(const int* __restrict__ row, const u16* __restrict__ esrc,
                           const float* __restrict__ mg, const float* __restrict__ dinv,
                           const float* __restrict__ w2m, float* __restrict__ out, int N) {
    int v = blockIdx.x * blockDim.x + threadIdx.x;
    if (v >= N) return;
    float acc = mg[v];
    int jb = row[v], je = row[v + 1];
    int j = jb;
    for (; j + 8 <= je; j += 8) {
        acc += mg[esrc[j]] + mg[esrc[j + 1]] + mg[esrc[j + 2]] + mg[esrc[j + 3]] +
               mg[esrc[j + 4]] + mg[esrc[j + 5]] + mg[esrc[j + 6]] + mg[esrc[j + 7]];
    }
    for (; j < je; j++) acc += mg[esrc[j]];
    out[v] = dinv[v] * acc + w2m[128];
}

extern "C" void kernel_launch(void* const* d_in, const int* in_sizes, int n_in,
                              void* d_out, int out_size, void* d_ws, size_t ws_size,
                              hipStream_t stream) {
    const float* x  = (const float*)d_in[0];
    const int* ei   = (const int*)d_in[1];
    const float* W1 = (const float*)d_in[2];
    const float* b1 = (const float*)d_in[3];
    const float* W2 = (const float*)d_in[4];
    const float* b2 = (const float*)d_in[5];
    float* out = (float*)d_out;

    const int N = N_NODES;
    const int E = in_sizes[1] / 2;
    const int* src = ei;
    const int* dst = ei + E;
    const int CHN = (E + CHUNK - 1) / CHUNK;   // 391
    const int nblocks = (N + 255) / 256;       // 196

    // workspace layout (4B units). EB aliases g16 (EB dead before gemm writes g16).
    float*    dinv = (float*)d_ws;                        // [NPAD]
    int*      row  = (int*)(dinv + NPAD);                 // [N+1 -> NPAD+16]
    uint*     B    = (uint*)(row + NPAD + 16);            // [256] (BK+1 used)
    float*    w2m  = (float*)(B + 256);                   // [256] ([128]=mean b2)
    float*    mg   = w2m + 256;                           // [NPAD]
    uint*     T    = (uint*)(mg + NPAD);                  // [256]
    uint*     H    = T + 256;                             // [BK*CHN]
    u16*      esrc = (u16*)(H + BK * CHN);                // [E] u16
    uint*     g16  = (uint*)(esrc + E + (E & 1));         // [NPAD*64]
    uint*     EB   = g16;                                 // [E] alias

    // CSR build: hist -> scans -> scatter -> per-bucket counting sort
    hist_kernel<<<CHN, 256, 0, stream>>>(dst, H, E, CHN);
    colscan_kernel<<<BK, 256, 0, stream>>>(H, T, CHN);
    totscan_kernel<<<1, 256, 0, stream>>>(T, B, row, E, N);
    scatter_kernel<<<CHN, 256, 0, stream>>>(src, dst, H, B, EB, E, CHN);
    bucket_sort_kernel<<<BK, 256, 0, stream>>>(EB, B, row, dinv, esrc, N);

    // w2m / mean(b2)
    w2m_kernel<<<129, 64, 0, stream>>>(W2, b2, w2m);

    // g16 = bf16( dinv * (x @ W1) )   (overwrites EB alias)
    gemm_kernel<<<(N + TM - 1) / TM, 256, 0, stream>>>(x, W1, g16, dinv, N);

    // mg[v] = dinv[v] * dot(leakyrelu(dinv[v]*(g[v]+sum g[nbr]) + b1), w2m)
    gather_node_kernel<<<(N + 3) / 4, 256, 0, stream>>>(row, esrc, g16, dinv, b1, w2m, mg, N);

    // out[v] = dinv[v] * (mg[v] + sum mg[nbr]) + mean(b2)
    out_kernel<<<nblocks, 256, 0, stream>>>(row, esrc, mg, dinv, w2m, out, N);
}

// Round 7
// 217.079 us; speedup vs baseline: 1.7166x; 1.1029x over previous
//
#include <hip/hip_runtime.h>
#include <hip/hip_bf16.h>

// GCN: 2x GCNConv(128->128) + LeakyReLU(0.1) + mean over channels.
// N=50000, E=1600000, D=128, fp32 in/out.
//
// R7: (a) GEMM1 -> MFMA bf16 (16x16x32): x/W1 cast to bf16, fp32 acc.
//     Error budget: adds ~same as existing bf16 g-packing (+~5e-5), under
//     2.47e-4 threshold. fp32 VALU gemm was ~50us at 27% VALUBusy.
//     (b) gather restructured for MLP: 8 chains x 8 lanes x 2 uint4/edge,
//     2-deep pipeline -> 16-32 loads in flight (was 8; 63us latency-bound,
//     FETCH 208MB @3.37TB/s with L3 ceiling much higher).
//     CSR build: R6 bucket sort (atomic-free, LDS only) kept unchanged.
// Math (verified R2-R6): g[u]=dinv[u]*(x@W1)[u]  (bf16-packed);
//   mg[u]=dinv[u]*dot(lrelu(dinv[u]*(g[u]+sum g[nbr]) + b1), mean_j W2[:,j]);
//   out[v]=dinv[v]*(mg[v]+sum mg[nbr]) + mean(b2).

#define N_NODES 50000
#define NPAD 50048
#define D 128
#define BK 196           // node buckets: v>>8
#define CHUNK 4096       // edges per stage-1 block

typedef unsigned int uint;
typedef unsigned short u16;
typedef __attribute__((ext_vector_type(8))) short short8;   // 8 bf16 (4 VGPRs)
typedef __attribute__((ext_vector_type(4))) float floatx4;

__device__ __forceinline__ u16 cvt_bf16(float f) {
    uint u = __float_as_uint(f);
    return (u16)((u + 0x7fffu + ((u >> 16) & 1u)) >> 16);   // RNE
}
__device__ __forceinline__ uint pack_bf2(float a, float b) {
    return (uint)cvt_bf16(a) | ((uint)cvt_bf16(b) << 16);
}

// ---------------- stage 1: per-chunk bucket histogram (LDS atomics) ----------------
__global__ void hist_kernel(const int* __restrict__ dst, uint* __restrict__ H, int E, int CHN) {
    __shared__ uint h[BK];
    int t = threadIdx.x, c = blockIdx.x;
    if (t < BK) h[t] = 0;
    __syncthreads();
    int e0 = c * CHUNK;
    for (int i = t; i < CHUNK; i += 256) {
        int e = e0 + i;
        if (e < E) atomicAdd(&h[dst[e] >> 8], 1u);
    }
    __syncthreads();
    if (t < BK) H[t * CHN + c] = h[t];     // bucket-major for column scan
}

// per-bucket exclusive scan over chunks (in place); totals -> T
__global__ void colscan_kernel(uint* __restrict__ H, uint* __restrict__ T, int CHN) {
    __shared__ uint s[256];
    int t = threadIdx.x, b = blockIdx.x;
    uint carry = 0;
    for (int base = 0; base < CHN; base += 256) {
        int idx = base + t;
        uint v = (idx < CHN) ? H[b * CHN + idx] : 0u;
        s[t] = v;
        __syncthreads();
#pragma unroll
        for (int off = 1; off < 256; off <<= 1) {
            uint u = (t >= off) ? s[t - off] : 0u;
            __syncthreads();
            s[t] += u;
            __syncthreads();
        }
        if (idx < CHN) H[b * CHN + idx] = carry + s[t] - v;   // exclusive + carry
        carry += s[255];
        __syncthreads();
    }
    if (t == 0) T[b] = carry;
}

// exclusive scan of bucket totals -> B[0..BK]; row[N]=E
__global__ void totscan_kernel(const uint* __restrict__ T, uint* __restrict__ B,
                               int* __restrict__ row, int E, int N) {
    __shared__ uint s[256];
    int t = threadIdx.x;
    uint v = (t < BK) ? T[t] : 0u;
    s[t] = v;
    __syncthreads();
#pragma unroll
    for (int off = 1; off < 256; off <<= 1) {
        uint u = (t >= off) ? s[t - off] : 0u;
        __syncthreads();
        s[t] += u;
        __syncthreads();
    }
    if (t < BK) B[t] = s[t] - v;
    if (t == 0) { B[BK] = (uint)E; row[N] = E; }
}

// scatter edges into bucket regions (LDS cursors)
__global__ void scatter_kernel(const int* __restrict__ src, const int* __restrict__ dst,
                               const uint* __restrict__ H, const uint* __restrict__ B,
                               uint* __restrict__ EB, int E, int CHN) {
    __shared__ uint cur[BK];
    int t = threadIdx.x, c = blockIdx.x;
    if (t < BK) cur[t] = B[t] + H[t * CHN + c];
    __syncthreads();
    int e0 = c * CHUNK;
    for (int i = t; i < CHUNK; i += 256) {
        int e = e0 + i;
        if (e < E) {
            int d = dst[e];
            uint slot = atomicAdd(&cur[d >> 8], 1u);
            EB[slot] = ((uint)(d & 255) << 16) | (uint)src[e];
        }
    }
}

// stage 2: per-bucket counting sort by dst&255 -> esrc, row, dinv (dense writes)
__global__ void bucket_sort_kernel(const uint* __restrict__ EB, const uint* __restrict__ B,
                                   int* __restrict__ row, float* __restrict__ dinv,
                                   u16* __restrict__ esrc, int N) {
    __shared__ uint cnt[256], s[256], cur[256];
    int t = threadIdx.x, b = blockIdx.x;
    uint base = B[b], ne = B[b + 1] - base;
    cnt[t] = 0;
    __syncthreads();
    for (uint i = t; i < ne; i += 256) atomicAdd(&cnt[EB[base + i] >> 16], 1u);
    __syncthreads();
    uint c = cnt[t];
    s[t] = c;
    __syncthreads();
#pragma unroll
    for (int off = 1; off < 256; off <<= 1) {
        uint u = (t >= off) ? s[t - off] : 0u;
        __syncthreads();
        s[t] += u;
        __syncthreads();
    }
    uint p = s[t] - c;                      // exclusive prefix within bucket
    int v = (b << 8) + t;
    if (v < N) {
        row[v] = (int)(base + p);
        dinv[v] = rsqrtf((float)(c + 1u));  // +1 self-loop
    }
    cur[t] = base + p;
    __syncthreads();
    for (uint i = t; i < ne; i += 256) {
        uint u = EB[base + i];
        uint slot = atomicAdd(&cur[u >> 16], 1u);
        esrc[slot] = (u16)(u & 0xffffu);
    }
}

// ---------------- w2m[k] = mean_j W2[k,j]; w2m[128] = mean(b2) ----------------
__global__ void w2m_kernel(const float* __restrict__ W2, const float* __restrict__ b2,
                           float* __restrict__ w2m) {
    int k = blockIdx.x, lane = threadIdx.x;   // grid 129 x 64
    const float* p = (k < 128) ? (W2 + k * 128) : b2;
    float s = p[lane] + p[lane + 64];
#pragma unroll
    for (int off = 32; off > 0; off >>= 1) s += __shfl_down(s, off, 64);
    if (lane == 0) w2m[k] = s * (1.0f / 128.0f);
}

// ---------------- MFMA GEMM: g16[M,128] = bf16( dinv[row] * (x @ W1) ) ----------------
// 4 waves x 16 rows per block; W1^T staged bf16 in LDS (stride 136, 16B-aligned
// b128 reads); A-frags loaded from global fp32 + cvt (x streamed once).
#define WT_STRIDE 136
__global__ __launch_bounds__(256) void gemm_mfma_kernel(
    const float* __restrict__ A, const float* __restrict__ W,
    u16* __restrict__ G16, const float* __restrict__ dinv, int M) {
    __shared__ u16 Wt[128 * WT_STRIDE];    // 34.8 KB
    int t = threadIdx.x;
    // stage W^T as bf16: W[k][n] -> Wt[n][k]  (global reads coalesced)
    for (int i = t; i < 128 * 128; i += 256) {
        int k = i >> 7, n = i & 127;
        Wt[n * WT_STRIDE + k] = cvt_bf16(W[i]);
    }
    __syncthreads();

    int wave = t >> 6, lane = t & 63;
    int m = lane & 15, quad = lane >> 4;
    int rowa = blockIdx.x * 64 + wave * 16 + m;          // A row this lane loads
    int rowc = rowa < M ? rowa : M - 1;
    const float* Arow = A + (long)rowc * D;

    // A fragments: A[m=lane&15][k = quad*8 + j], 4 k-tiles
    short8 afrag[4];
#pragma unroll
    for (int kt = 0; kt < 4; kt++) {
        int k0 = kt * 32 + quad * 8;
        float4 f0 = *(const float4*)(Arow + k0);
        float4 f1 = *(const float4*)(Arow + k0 + 4);
        short8 af;
        af[0] = (short)cvt_bf16(f0.x); af[1] = (short)cvt_bf16(f0.y);
        af[2] = (short)cvt_bf16(f0.z); af[3] = (short)cvt_bf16(f0.w);
        af[4] = (short)cvt_bf16(f1.x); af[5] = (short)cvt_bf16(f1.y);
        af[6] = (short)cvt_bf16(f1.z); af[7] = (short)cvt_bf16(f1.w);
        afrag[kt] = af;
    }

    // output rows for this lane: orow0 + quad*4 + r  (C: col=lane&15, row=quad*4+reg)
    int orow0 = blockIdx.x * 64 + wave * 16;
    float dv[4]; bool ok[4];
#pragma unroll
    for (int r = 0; r < 4; r++) {
        int orow = orow0 + quad * 4 + r;
        ok[r] = orow < M;
        dv[r] = dinv[ok[r] ? orow : (M - 1)];
    }

    uint* G32 = (uint*)G16;
    for (int n0 = 0; n0 < 128; n0 += 16) {
        floatx4 acc = {0.f, 0.f, 0.f, 0.f};
#pragma unroll
        for (int kt = 0; kt < 4; kt++) {
            short8 bf = *(const short8*)(Wt + (n0 + m) * WT_STRIDE + kt * 32 + quad * 8);
            acc = __builtin_amdgcn_mfma_f32_16x16x32_bf16(afrag[kt], bf, acc, 0, 0, 0);
        }
#pragma unroll
        for (int r = 0; r < 4; r++) {
            float val = acc[r] * dv[r];
            float oth = __shfl_xor(val, 1, 64);          // partner column
            if (ok[r] && (m & 1) == 0) {
                int orow = orow0 + quad * 4 + r;
                G32[(long)orow * 64 + ((n0 + m) >> 1)] = pack_bf2(val, oth);
            }
        }
    }
}

// ---------------- fused gather(bf16) + leakyrelu + dot(w2m) ----------------
// One wave/node; 8 chains x 8 lanes; each lane: 2 independent uint4 per edge,
// 2-deep pipeline -> 16-32 loads in flight per wave.
__global__ __launch_bounds__(256) void gather_node_kernel(
    const int* __restrict__ row, const u16* __restrict__ esrc,
    const uint* __restrict__ g16, const float* __restrict__ dinv,
    const float* __restrict__ b1, const float* __restrict__ w2m,
    float* __restrict__ mg, int N) {
    int wave = threadIdx.x >> 6;
    int lane = threadIdx.x & 63;
    int sub = lane & 7;        // 16-channel slice: uint4 pair 2*sub, 2*sub+1
    int nb = lane >> 3;        // 8 neighbor chains
    int v = blockIdx.x * 4 + wave;
    if (v >= N) return;

    const uint4* gv = (const uint4*)g16;   // 16 uint4 per 256B row
    float acc[16];
#pragma unroll
    for (int i = 0; i < 16; i++) acc[i] = 0.f;

#define ACC8(ua, ub) {                                                   \
    uint uu[8] = {(ua).x, (ua).y, (ua).z, (ua).w, (ub).x, (ub).y, (ub).z, (ub).w}; \
    _Pragma("unroll")                                                    \
    for (int i = 0; i < 8; i++) {                                        \
        acc[2*i]   += __uint_as_float(uu[i] << 16);                      \
        acc[2*i+1] += __uint_as_float(uu[i] & 0xffff0000u);              \
    } }

    if (nb == 0) {             // self-loop term
        long rb = (long)v * 16 + 2 * sub;
        uint4 ua = gv[rb], ub = gv[rb + 1];
        ACC8(ua, ub)
    }
    int jb = row[v], je = row[v + 1];
    int j = jb + nb;
    if (j < je) {
        long r0 = (long)esrc[j] * 16 + 2 * sub;
        uint4 p0 = gv[r0], p1 = gv[r0 + 1];
        j += 8;
        while (j < je) {
            long r1 = (long)esrc[j] * 16 + 2 * sub;
            uint4 q0 = gv[r1], q1 = gv[r1 + 1];
            j += 8;
            ACC8(p0, p1)
            p0 = q0; p1 = q1;
        }
        ACC8(p0, p1)
    }
#undef ACC8

    // reduce the 8 chains
#pragma unroll
    for (int i = 0; i < 16; i++) {
        acc[i] += __shfl_xor(acc[i], 8, 64);
        acc[i] += __shfl_xor(acc[i], 16, 64);
        acc[i] += __shfl_xor(acc[i], 32, 64);
    }

    if (nb == 0) {             // lane sub holds channels 16*sub .. 16*sub+15
        float dvv = dinv[v];
        const float4* bp = (const float4*)b1;
        const float4* wp = (const float4*)w2m;
        float s = 0.f;
#pragma unroll
        for (int q4 = 0; q4 < 4; q4++) {
            float4 bb = bp[sub * 4 + q4];
            float4 wm = wp[sub * 4 + q4];
            float t0 = dvv * acc[4*q4 + 0] + bb.x; t0 = t0 >= 0.f ? t0 : 0.1f * t0;
            float t1 = dvv * acc[4*q4 + 1] + bb.y; t1 = t1 >= 0.f ? t1 : 0.1f * t1;
            float t2 = dvv * acc[4*q4 + 2] + bb.z; t2 = t2 >= 0.f ? t2 : 0.1f * t2;
            float t3 = dvv * acc[4*q4 + 3] + bb.w; t3 = t3 >= 0.f ? t3 : 0.1f * t3;
            s += t0 * wm.x + t1 * wm.y + t2 * wm.z + t3 * wm.w;
        }
        s += __shfl_xor(s, 1, 64);
        s += __shfl_xor(s, 2, 64);
        s += __shfl_xor(s, 4, 64);
        if (sub == 0) mg[v] = dvv * s;
    }
}

// ---------------- scalar aggregate for conv2 + mean ----------------
__global__ void out_kernel(const int* __restrict__ row, const u16* __restrict__ esrc,
                           const float* __restrict__ mg, const float* __restrict__ dinv,
                           const float* __restrict__ w2m, float* __restrict__ out, int N) {
    int v = blockIdx.x * blockDim.x + threadIdx.x;
    if (v >= N) return;
    float acc = mg[v];
    int jb = row[v], je = row[v + 1];
    int j = jb;
    for (; j + 8 <= je; j += 8) {
        acc += mg[esrc[j]] + mg[esrc[j + 1]] + mg[esrc[j + 2]] + mg[esrc[j + 3]] +
               mg[esrc[j + 4]] + mg[esrc[j + 5]] + mg[esrc[j + 6]] + mg[esrc[j + 7]];
    }
    for (; j < je; j++) acc += mg[esrc[j]];
    out[v] = dinv[v] * acc + w2m[128];
}

extern "C" void kernel_launch(void* const* d_in, const int* in_sizes, int n_in,
                              void* d_out, int out_size, void* d_ws, size_t ws_size,
                              hipStream_t stream) {
    const float* x  = (const float*)d_in[0];
    const int* ei   = (const int*)d_in[1];
    const float* W1 = (const float*)d_in[2];
    const float* b1 = (const float*)d_in[3];
    const float* W2 = (const float*)d_in[4];
    const float* b2 = (const float*)d_in[5];
    float* out = (float*)d_out;

    const int N = N_NODES;
    const int E = in_sizes[1] / 2;
    const int* src = ei;
    const int* dst = ei + E;
    const int CHN = (E + CHUNK - 1) / CHUNK;   // 391
    const int nblocks = (N + 255) / 256;       // 196

    // workspace (4B units). g16 placed early for guaranteed 16B alignment;
    // EB aliases g16 (dead before gemm writes g16).
    float*    dinv = (float*)d_ws;                        // [NPAD]
    int*      row  = (int*)(dinv + NPAD);                 // [N+1 -> NPAD+16]
    uint*     B    = (uint*)(row + NPAD + 16);            // [256] (BK+1 used)
    float*    w2m  = (float*)(B + 256);                   // [256] ([128]=mean b2)
    float*    mg   = w2m + 256;                           // [NPAD]
    uint*     T    = (uint*)(mg + NPAD);                  // [256]
    uint*     g16u = T + 256;                             // [NPAD*64] = u16[NPAD][128]
    u16*      esrc = (u16*)(g16u + NPAD * 64);            // [E] u16
    uint*     H    = (uint*)(esrc + E + (E & 1));         // [BK*CHN]
    uint*     EB   = g16u;                                // [E] alias

    // CSR build: hist -> scans -> scatter -> per-bucket counting sort
    hist_kernel<<<CHN, 256, 0, stream>>>(dst, H, E, CHN);
    colscan_kernel<<<BK, 256, 0, stream>>>(H, T, CHN);
    totscan_kernel<<<1, 256, 0, stream>>>(T, B, row, E, N);
    scatter_kernel<<<CHN, 256, 0, stream>>>(src, dst, H, B, EB, E, CHN);
    bucket_sort_kernel<<<BK, 256, 0, stream>>>(EB, B, row, dinv, esrc, N);

    // w2m / mean(b2)
    w2m_kernel<<<129, 64, 0, stream>>>(W2, b2, w2m);

    // g16 = bf16( dinv * (x @ W1) ) via MFMA   (overwrites EB alias)
    gemm_mfma_kernel<<<(N + 63) / 64, 256, 0, stream>>>(x, W1, (u16*)g16u, dinv, N);

    // mg[v] = dinv[v] * dot(leakyrelu(dinv[v]*(g[v]+sum g[nbr]) + b1), w2m)
    gather_node_kernel<<<(N + 3) / 4, 256, 0, stream>>>(row, esrc, g16u, dinv, b1, w2m, mg, N);

    // out[v] = dinv[v] * (mg[v] + sum mg[nbr]) + mean(b2)
    out_kernel<<<nblocks, 256, 0, stream>>>(row, esrc, mg, dinv, w2m, out, N);
}